// Round 6
// baseline (346.716 us; speedup 1.0000x reference)
//
#include <hip/hip_runtime.h>
#include <hip/hip_bf16.h>

#define Bb 256
#define Ss 2048
#define Tt 48
#define NCK 32           // chunks per batch (pws = 37.7 MB; ws >= ~97 MB proven in r1)
#define CLEN 64          // steps per chunk (last chunk: 63)

static constexpr float C_SHIFT = 4.875f;  // ~ln(48)+1: per-step growth ~= 1

typedef float f4   __attribute__((ext_vector_type(4)));
typedef short s4h  __attribute__((ext_vector_type(4)));
typedef __bf16 bf16x8 __attribute__((ext_vector_type(8)));

union U32x4 { unsigned u[4]; bf16x8 v; };
union U32x2 { unsigned u[2]; s4h v; };

__device__ __forceinline__ unsigned pk_trunc(float lo, float hi) {
    unsigned a = __builtin_bit_cast(unsigned, lo);
    unsigned b = __builtin_bit_cast(unsigned, hi);
#if __has_builtin(__builtin_amdgcn_perm)
    return __builtin_amdgcn_perm(b, a, 0x07060302u);
#else
    return (b & 0xFFFF0000u) | (a >> 16);
#endif
}
__device__ __forceinline__ unsigned pk_rne(float lo, float hi) {
    __hip_bfloat162 h = __float22bfloat162_rn(make_float2(lo, hi));
    union { __hip_bfloat16 b[2]; unsigned u; } t;
    t.b[0] = h.x; t.b[1] = h.y;
    return t.u;
}
__device__ __forceinline__ float bfu(unsigned u) { return __builtin_bit_cast(float, u); }

// k-slot bijection for the x32 operands: slot (g,j) holds k = sig32(g,j).
// Chosen so the step's C-output (row = 16*mt + 4g + r at lane-quad g) repacks
// into next step's B operands with ZERO cross-lane traffic:
//   sig32(g,j) = 16*(j>>2) + 4g + (j&3)   (j<4 -> rows of m-tile 0, j>=4 -> m-tile 1)
//   x16 frag covers rows 32..47: slot (g,r) = 32 + 4g + r  (m-tile 2)
// A and B use the same slot convention, so the MFMA contracts correctly for
// ANY bijection (hardware pairs equal slots of A and B).
__device__ __forceinline__ int sig32(int g, int j) {
    return 16 * (j >> 2) + 4 * g + (j & 3);
}

#define MFMA32(a,b,c) __builtin_amdgcn_mfma_f32_16x16x32_bf16(a, b, c, 0, 0, 0)
#define MFMA16(a,b,c) __builtin_amdgcn_mfma_f32_16x16x16bf16_1k(a, b, c, 0, 0, 0)

// ---------------------------------------------------------------------------
// One scan step: per n-tile, D = A32*B32 (K rows 0..31) + A16*B16 (rows
// 32..47), rowscale by e, repack (natural row space throughout).
// ---------------------------------------------------------------------------
__device__ __forceinline__ void scan_step(const bf16x8 (&A32)[3], const s4h (&A16)[3],
                                          bf16x8 (&B32)[3], s4h (&B16)[3],
                                          const float* __restrict__ eb)
{
    f4 e0 = *(const f4*)(eb);          // e[4g + 0..3]      (rows of m-tile 0)
    f4 e1 = *(const f4*)(eb + 16);     // e[16 + 4g + 0..3] (m-tile 1)
    f4 e2 = *(const f4*)(eb + 32);     // e[32 + 4g + 0..3] (m-tile 2)
    const f4 z = {0.f, 0.f, 0.f, 0.f};
#pragma unroll
    for (int nt = 0; nt < 3; ++nt) {
        f4 c0v = MFMA32(A32[0], B32[nt], z);
        f4 c1v = MFMA32(A32[1], B32[nt], z);
        f4 c2v = MFMA32(A32[2], B32[nt], z);
        c0v = MFMA16(A16[0], B16[nt], c0v);
        c1v = MFMA16(A16[1], B16[nt], c1v);
        c2v = MFMA16(A16[2], B16[nt], c2v);
        // repack: B32 slot j<4 <- m-tile0 reg j (row 4g+j); j>=4 <- m-tile1 reg j-4
        U32x4 nb;
        nb.u[0] = pk_trunc(c0v[0] * e0[0], c0v[1] * e0[1]);
        nb.u[1] = pk_trunc(c0v[2] * e0[2], c0v[3] * e0[3]);
        nb.u[2] = pk_trunc(c1v[0] * e1[0], c1v[1] * e1[1]);
        nb.u[3] = pk_trunc(c1v[2] * e1[2], c1v[3] * e1[3]);
        B32[nt] = nb.v;
        U32x2 nc;
        nc.u[0] = pk_trunc(c2v[0] * e2[0], c2v[1] * e2[1]);
        nc.u[1] = pk_trunc(c2v[2] * e2[2], c2v[3] * e2[3]);
        B16[nt] = nc.v;
    }
}

// ---------------------------------------------------------------------------
// Phase 1: one wave per (batch, chunk): 48x48 transfer-matrix product in regs.
// 2048 blocks x 4 waves = 8192 waves = 256 batches x 32 chunks.
// 8 blocks/CU (launch_bounds cap 64 VGPR -> 8 waves/SIMD; LDS 96 KB/CU).
// ---------------------------------------------------------------------------
__global__ __launch_bounds__(256, 8)
void crf_scan(const float* __restrict__ em, const float* __restrict__ trn,
              float* __restrict__ pws, float* __restrict__ outz)
{
    __shared__ float lex[4][16 * Tt];          // per-wave 16-step exp(em) buffer
    const int tid = threadIdx.x, wv = tid >> 6, l = tid & 63;
    const int c0 = l & 15, g = l >> 4;
    const int wid = blockIdx.x * 4 + wv;
    const int b = wid >> 5, ck = wid & (NCK - 1);
    if (blockIdx.x == 0 && tid == 0) outz[0] = 0.0f;   // zero d_out for finish

    // A-frags: A32[mt] slot (g,j) = exp(trn[sig32(g,j)][16mt+c0])
    //          A16[mt] slot (g,j) = exp(trn[32+4g+j][16mt+c0])
    bf16x8 A32[3]; s4h A16[3];
#pragma unroll
    for (int mt = 0; mt < 3; ++mt) {
        float v[8];
#pragma unroll
        for (int j = 0; j < 8; ++j)
            v[j] = __expf(trn[sig32(g, j) * Tt + 16 * mt + c0]);
        U32x4 a;
        a.u[0] = pk_rne(v[0], v[1]); a.u[1] = pk_rne(v[2], v[3]);
        a.u[2] = pk_rne(v[4], v[5]); a.u[3] = pk_rne(v[6], v[7]);
        A32[mt] = a.v;
        float w0 = __expf(trn[(32 + 4 * g + 0) * Tt + 16 * mt + c0]);
        float w1 = __expf(trn[(32 + 4 * g + 1) * Tt + 16 * mt + c0]);
        float w2 = __expf(trn[(32 + 4 * g + 2) * Tt + 16 * mt + c0]);
        float w3 = __expf(trn[(32 + 4 * g + 3) * Tt + 16 * mt + c0]);
        U32x2 c;
        c.u[0] = pk_rne(w0, w1); c.u[1] = pk_rne(w2, w3);
        A16[mt] = c.v;
    }

    // State init = identity: B32 slot (g,j) hot iff sig32(g,j) == 16nt + c0
    bf16x8 B32[3]; s4h B16[3];
#pragma unroll
    for (int nt = 0; nt < 3; ++nt) {
        U32x4 bi;
#pragma unroll
        for (int q = 0; q < 4; ++q) {
            unsigned lo = (sig32(g, 2 * q)     == 16 * nt + c0) ? 0x3F80u : 0u;
            unsigned hi = (sig32(g, 2 * q + 1) == 16 * nt + c0) ? 0x3F80u : 0u;
            bi.u[q] = lo | (hi << 16);
        }
        B32[nt] = bi.v;
        U32x2 ci;
#pragma unroll
        for (int q = 0; q < 2; ++q) {
            unsigned lo = (nt == 2 && 4 * g + 2 * q     == c0) ? 0x3F80u : 0u;
            unsigned hi = (nt == 2 && 4 * g + 2 * q + 1 == c0) ? 0x3F80u : 0u;
            ci.u[q] = lo | (hi << 16);
        }
        B16[nt] = ci.v;
    }

    const int total = (ck == NCK - 1) ? (CLEN - 1) : CLEN;   // 64 / 63
    const int s0 = ck * CLEN + 1;
    const float* emb = em + (size_t)b * (Ss * Tt);
    float* lw = &lex[wv][0];
    const float* lexg = lw + g * 4;
    const long lim = (long)Ss * Tt - 4;

    // prefetch sub 0 (early-issued global loads, consumed at loop top)
    f4 r[3];
#pragma unroll
    for (int i = 0; i < 3; ++i) {
        long o = (long)s0 * Tt + l * 4 + i * 256;
        if (o > lim) o = lim;
        r[i] = *(const f4*)(emb + o);
    }

    const int nsub = (total + 15) >> 4;
    for (int sub = 0; sub < nsub; ++sub) {
#pragma unroll
        for (int i = 0; i < 3; ++i)
#pragma unroll
            for (int j = 0; j < 4; ++j) r[i][j] = __expf(r[i][j] - C_SHIFT);
#pragma unroll
        for (int i = 0; i < 3; ++i) *(f4*)(lw + l * 4 + i * 256) = r[i];

        if (sub + 1 < nsub) {        // issue next sub's loads before compute
#pragma unroll
            for (int i = 0; i < 3; ++i) {
                long o = (long)(s0 + (sub + 1) * 16) * Tt + l * 4 + i * 256;
                if (o > lim) o = lim;
                r[i] = *(const f4*)(emb + o);
            }
        }

        int nsteps = total - sub * 16;
        if (nsteps >= 16) {
#pragma unroll
            for (int u = 0; u < 16; ++u)
                scan_step(A32, A16, B32, B16, lexg + u * Tt);
        } else {
            for (int u = 0; u < nsteps; ++u)
                scan_step(A32, A16, B32, B16, lexg + u * Tt);
        }
    }

    // store 18 u32/lane, coalesced. Word (nt*6+q): q=0..3 -> rows sig32(g,2q),
    // sig32(g,2q+1); q=4,5 -> rows 32+4g+{0,1},{2,3}; col = 16nt+c0.
    unsigned* pw = (unsigned*)pws + (size_t)wid * 1152 + l;
#pragma unroll
    for (int nt = 0; nt < 3; ++nt) {
        U32x4 a; a.v = B32[nt];
        U32x2 c; c.v = B16[nt];
        pw[(nt * 6 + 0) * 64] = a.u[0];
        pw[(nt * 6 + 1) * 64] = a.u[1];
        pw[(nt * 6 + 2) * 64] = a.u[2];
        pw[(nt * 6 + 3) * 64] = a.u[3];
        pw[(nt * 6 + 4) * 64] = c.u[0];
        pw[(nt * 6 + 5) * 64] = c.u[1];
    }
}

// ---------------------------------------------------------------------------
// Phase 2 + gold, merged: one block per batch; wave 0 chains the NCK chunk
// matrices with renorm, combines with gold. y[4t+r] <-> row 16t+4g+r.
// ---------------------------------------------------------------------------
__global__ __launch_bounds__(256)
void crf_finish(const float* __restrict__ em, const int* __restrict__ tags,
                const int* __restrict__ mask, const float* __restrict__ trn,
                const float* __restrict__ stt, const float* __restrict__ ent,
                const float* __restrict__ pws, float* __restrict__ out)
{
    __shared__ float red[256];
    __shared__ float alpha[Tt];
    const int b = blockIdx.x, t = threadIdx.x;

    // gold partial
    const int* tg = tags + (size_t)b * Ss;
    float local = 0.0f;
    for (int s = t; s < Ss; s += 256) {
        if (s > 0) {
            int pv = tg[s - 1], cu = tg[s];
            float mf = (float)mask[(size_t)b * Ss + s];
            local += (trn[pv * Tt + cu] + em[((size_t)b * Ss + s) * Tt + cu]) * mf;
        }
    }
    if (t == 0) {
        int t0 = tg[0];
        local += stt[t0] + em[(size_t)b * Ss * Tt + t0];
        local += ent[tg[Ss - 1]];
    }
    red[t] = local;
    __syncthreads();
    if (t < 128) red[t] += red[t + 128];
    __syncthreads();

    if (t < 64) {
        const int l = t, c0 = l & 15, g = l >> 4;
        float gsum = red[l] + red[l + 64];
#pragma unroll
        for (int m = 32; m >= 1; m >>= 1) gsum += __shfl_xor(gsum, m);

        // alpha init (natural): alpha[i] = exp(stt[i] + em[b,0,i] - C)
        if (l < Tt) alpha[l] = __expf(stt[l] + em[(size_t)b * Ss * Tt + l] - C_SHIFT);

        float acc = 0.0f;
        const unsigned* pw = (const unsigned*)pws + (size_t)b * NCK * 1152 + l;
        for (int ck = 0; ck < NCK; ++ck) {
            float y[12];
#pragma unroll
            for (int i = 0; i < 12; ++i) y[i] = 0.0f;
#pragma unroll
            for (int nt = 0; nt < 3; ++nt) {
                float av = alpha[16 * nt + c0];
                unsigned w[6];
#pragma unroll
                for (int q = 0; q < 6; ++q) w[q] = pw[(size_t)ck * 1152 + (nt * 6 + q) * 64];
                // q=0,1 -> y[0..3]; q=2,3 -> y[4..7]; q=4,5 -> y[8..11]
#pragma unroll
                for (int q = 0; q < 6; ++q) {
                    y[2 * q]     += bfu(w[q] << 16)         * av;
                    y[2 * q + 1] += bfu(w[q] & 0xFFFF0000u) * av;
                }
            }
#pragma unroll
            for (int m = 1; m <= 8; m <<= 1)
#pragma unroll
                for (int i = 0; i < 12; ++i) y[i] += __shfl_xor(y[i], m);
            float mx = y[0];
#pragma unroll
            for (int i = 1; i < 12; ++i) mx = fmaxf(mx, y[i]);
            mx = fmaxf(mx, __shfl_xor(mx, 16));
            mx = fmaxf(mx, __shfl_xor(mx, 32));
            acc += __logf(mx);
            float rm = 1.0f / mx;
            if (c0 == 0) {
#pragma unroll
                for (int tt = 0; tt < 3; ++tt)
#pragma unroll
                    for (int rr = 0; rr < 4; ++rr)
                        alpha[16 * tt + 4 * g + rr] = y[4 * tt + rr] * rm;
            }
        }
        // fwd = log(sum alpha * exp(ent)) + acc + S*C
        float part = (l < Tt) ? alpha[l] * __expf(ent[l]) : 0.0f;
#pragma unroll
        for (int m = 32; m >= 1; m >>= 1) part += __shfl_xor(part, m);
        if (t == 0) {
            float fwd = __logf(part) + acc + (float)Ss * C_SHIFT;
            atomicAdd(out, (fwd - gsum) * (1.0f / 256.0f));
        }
    }
}

// ---------------------------------------------------------------------------
extern "C" void kernel_launch(void* const* d_in, const int* in_sizes, int n_in,
                              void* d_out, int out_size, void* d_ws, size_t ws_size,
                              hipStream_t stream)
{
    const float* em  = (const float*)d_in[0];
    const int* tags  = (const int*)d_in[1];
    const int* mask  = (const int*)d_in[2];
    const float* trn = (const float*)d_in[3];
    const float* stt = (const float*)d_in[4];
    const float* ent = (const float*)d_in[5];
    float* out = (float*)d_out;
    float* pws = (float*)d_ws;   // 8192 waves x 4608 B = 37.7 MB

    crf_scan<<<2048, 256, 0, stream>>>(em, trn, pws, out);
    crf_finish<<<256, 256, 0, stream>>>(em, tags, mask, trn, stt, ent, pws, out);
}

// Round 7
// 256.235 us; speedup vs baseline: 1.3531x; 1.3531x over previous
//
#include <hip/hip_runtime.h>
#include <hip/hip_bf16.h>

#define Bb 256
#define Ss 2048
#define Tt 48
#define NCK 24           // chunks per batch (pws = 28.3 MB)
#define CLEN 86          // steps per chunk (last chunk: 69)

static constexpr float C_SHIFT = 4.875f;  // ~ln(48)+1: per-step growth ~= 1

typedef float f4   __attribute__((ext_vector_type(4)));
typedef short s4h  __attribute__((ext_vector_type(4)));
typedef __bf16 bf16x8 __attribute__((ext_vector_type(8)));

union U32x4 { unsigned u[4]; bf16x8 v; };
union U32x2 { unsigned u[2]; s4h v; };

__device__ __forceinline__ unsigned pk_trunc(float lo, float hi) {
    unsigned a = __builtin_bit_cast(unsigned, lo);
    unsigned b = __builtin_bit_cast(unsigned, hi);
#if __has_builtin(__builtin_amdgcn_perm)
    return __builtin_amdgcn_perm(b, a, 0x07060302u);
#else
    return (b & 0xFFFF0000u) | (a >> 16);
#endif
}
__device__ __forceinline__ unsigned pk_rne(float lo, float hi) {
    __hip_bfloat162 h = __float22bfloat162_rn(make_float2(lo, hi));
    union { __hip_bfloat16 b[2]; unsigned u; } t;
    t.b[0] = h.x; t.b[1] = h.y;
    return t.u;
}
__device__ __forceinline__ float bfu(unsigned u) { return __builtin_bit_cast(float, u); }

// k-slot bijection for the x32 operands: slot (g,j) holds k = sig32(g,j).
// Chosen so the step's C-output (row = 16*mt + 4g + r at lane-quad g) repacks
// into next step's B operands with ZERO cross-lane traffic:
//   sig32(g,j) = 16*(j>>2) + 4g + (j&3)   (j<4 -> rows of m-tile 0, j>=4 -> m-tile 1)
//   x16 frag covers rows 32..47: slot (g,r) = 32 + 4g + r  (m-tile 2)
// A and B use the same slot convention, so the MFMA contracts correctly for
// ANY bijection (hardware pairs equal slots of A and B).
__device__ __forceinline__ int sig32(int g, int j) {
    return 16 * (j >> 2) + 4 * g + (j & 3);
}

#define MFMA32(a,b,c) __builtin_amdgcn_mfma_f32_16x16x32_bf16(a, b, c, 0, 0, 0)
#define MFMA16(a,b,c) __builtin_amdgcn_mfma_f32_16x16x16bf16_1k(a, b, c, 0, 0, 0)

// ---------------------------------------------------------------------------
// One scan step: per n-tile, D = A32*B32 (K rows 0..31) + A16*B16 (rows
// 32..47), rowscale by e, repack (natural row space throughout).
// ---------------------------------------------------------------------------
__device__ __forceinline__ void scan_step(const bf16x8 (&A32)[3], const s4h (&A16)[3],
                                          bf16x8 (&B32)[3], s4h (&B16)[3],
                                          const float* __restrict__ eb)
{
    f4 e0 = *(const f4*)(eb);          // e[4g + 0..3]      (rows of m-tile 0)
    f4 e1 = *(const f4*)(eb + 16);     // e[16 + 4g + 0..3] (m-tile 1)
    f4 e2 = *(const f4*)(eb + 32);     // e[32 + 4g + 0..3] (m-tile 2)
    const f4 z = {0.f, 0.f, 0.f, 0.f};
#pragma unroll
    for (int nt = 0; nt < 3; ++nt) {
        f4 c0v = MFMA32(A32[0], B32[nt], z);
        f4 c1v = MFMA32(A32[1], B32[nt], z);
        f4 c2v = MFMA32(A32[2], B32[nt], z);
        c0v = MFMA16(A16[0], B16[nt], c0v);
        c1v = MFMA16(A16[1], B16[nt], c1v);
        c2v = MFMA16(A16[2], B16[nt], c2v);
        // repack: B32 slot j<4 <- m-tile0 reg j (row 4g+j); j>=4 <- m-tile1 reg j-4
        U32x4 nb;
        nb.u[0] = pk_trunc(c0v[0] * e0[0], c0v[1] * e0[1]);
        nb.u[1] = pk_trunc(c0v[2] * e0[2], c0v[3] * e0[3]);
        nb.u[2] = pk_trunc(c1v[0] * e1[0], c1v[1] * e1[1]);
        nb.u[3] = pk_trunc(c1v[2] * e1[2], c1v[3] * e1[3]);
        B32[nt] = nb.v;
        U32x2 nc;
        nc.u[0] = pk_trunc(c2v[0] * e2[0], c2v[1] * e2[1]);
        nc.u[1] = pk_trunc(c2v[2] * e2[2], c2v[3] * e2[3]);
        B16[nt] = nc.v;
    }
}

// ---------------------------------------------------------------------------
// Phase 1: one wave per (batch, chunk): 48x48 transfer-matrix product in regs.
// 1536 blocks x 4 waves = 6144 waves = 256 batches x 24 chunks.
// 6 blocks/CU (launch_bounds 256,6 -> VGPR cap ~85; kernel needs 64 -> NO
// spill; r6 proved cap 64 (256,8) forces VGPR=32 + 300 MB scratch spill).
// ---------------------------------------------------------------------------
__global__ __launch_bounds__(256, 6)
void crf_scan(const float* __restrict__ em, const float* __restrict__ trn,
              float* __restrict__ pws, float* __restrict__ outz)
{
    __shared__ float lex[4][16 * Tt];          // per-wave 16-step exp(em) buffer
    const int tid = threadIdx.x, wv = tid >> 6, l = tid & 63;
    const int c0 = l & 15, g = l >> 4;
    const int wid = blockIdx.x * 4 + wv;
    const int b = wid / NCK, ck = wid % NCK;
    if (blockIdx.x == 0 && tid == 0) outz[0] = 0.0f;   // zero d_out for finish

    // A-frags: A32[mt] slot (g,j) = exp(trn[sig32(g,j)][16mt+c0])
    //          A16[mt] slot (g,j) = exp(trn[32+4g+j][16mt+c0])
    bf16x8 A32[3]; s4h A16[3];
#pragma unroll
    for (int mt = 0; mt < 3; ++mt) {
        float v[8];
#pragma unroll
        for (int j = 0; j < 8; ++j)
            v[j] = __expf(trn[sig32(g, j) * Tt + 16 * mt + c0]);
        U32x4 a;
        a.u[0] = pk_rne(v[0], v[1]); a.u[1] = pk_rne(v[2], v[3]);
        a.u[2] = pk_rne(v[4], v[5]); a.u[3] = pk_rne(v[6], v[7]);
        A32[mt] = a.v;
        float w0 = __expf(trn[(32 + 4 * g + 0) * Tt + 16 * mt + c0]);
        float w1 = __expf(trn[(32 + 4 * g + 1) * Tt + 16 * mt + c0]);
        float w2 = __expf(trn[(32 + 4 * g + 2) * Tt + 16 * mt + c0]);
        float w3 = __expf(trn[(32 + 4 * g + 3) * Tt + 16 * mt + c0]);
        U32x2 c;
        c.u[0] = pk_rne(w0, w1); c.u[1] = pk_rne(w2, w3);
        A16[mt] = c.v;
    }

    // State init = identity: B32 slot (g,j) hot iff sig32(g,j) == 16nt + c0
    bf16x8 B32[3]; s4h B16[3];
#pragma unroll
    for (int nt = 0; nt < 3; ++nt) {
        U32x4 bi;
#pragma unroll
        for (int q = 0; q < 4; ++q) {
            unsigned lo = (sig32(g, 2 * q)     == 16 * nt + c0) ? 0x3F80u : 0u;
            unsigned hi = (sig32(g, 2 * q + 1) == 16 * nt + c0) ? 0x3F80u : 0u;
            bi.u[q] = lo | (hi << 16);
        }
        B32[nt] = bi.v;
        U32x2 ci;
#pragma unroll
        for (int q = 0; q < 2; ++q) {
            unsigned lo = (nt == 2 && 4 * g + 2 * q     == c0) ? 0x3F80u : 0u;
            unsigned hi = (nt == 2 && 4 * g + 2 * q + 1 == c0) ? 0x3F80u : 0u;
            ci.u[q] = lo | (hi << 16);
        }
        B16[nt] = ci.v;
    }

    const int total = (ck == NCK - 1) ? (Ss - 1 - ck * CLEN) : CLEN;  // 86 / 69
    const int s0 = ck * CLEN + 1;
    const float* emb = em + (size_t)b * (Ss * Tt);
    float* lw = &lex[wv][0];
    const float* lexg = lw + g * 4;
    const long lim = (long)Ss * Tt - 4;

    // prefetch sub 0 (early-issued global loads, consumed at loop top)
    f4 r[3];
#pragma unroll
    for (int i = 0; i < 3; ++i) {
        long o = (long)s0 * Tt + l * 4 + i * 256;
        if (o > lim) o = lim;
        r[i] = *(const f4*)(emb + o);
    }

    const int nsub = (total + 15) >> 4;
    for (int sub = 0; sub < nsub; ++sub) {
#pragma unroll
        for (int i = 0; i < 3; ++i)
#pragma unroll
            for (int j = 0; j < 4; ++j) r[i][j] = __expf(r[i][j] - C_SHIFT);
#pragma unroll
        for (int i = 0; i < 3; ++i) *(f4*)(lw + l * 4 + i * 256) = r[i];

        if (sub + 1 < nsub) {        // issue next sub's loads before compute
#pragma unroll
            for (int i = 0; i < 3; ++i) {
                long o = (long)(s0 + (sub + 1) * 16) * Tt + l * 4 + i * 256;
                if (o > lim) o = lim;
                r[i] = *(const f4*)(emb + o);
            }
        }

        int nsteps = total - sub * 16;
        if (nsteps >= 16) {
#pragma unroll
            for (int u = 0; u < 16; ++u)
                scan_step(A32, A16, B32, B16, lexg + u * Tt);
        } else {
            for (int u = 0; u < nsteps; ++u)
                scan_step(A32, A16, B32, B16, lexg + u * Tt);
        }
    }

    // store 18 u32/lane, coalesced. Word (nt*6+q): q=0..3 -> rows sig32(g,2q),
    // sig32(g,2q+1); q=4,5 -> rows 32+4g+{0,1},{2,3}; col = 16nt+c0.
    unsigned* pw = (unsigned*)pws + (size_t)wid * 1152 + l;
#pragma unroll
    for (int nt = 0; nt < 3; ++nt) {
        U32x4 a; a.v = B32[nt];
        U32x2 c; c.v = B16[nt];
        pw[(nt * 6 + 0) * 64] = a.u[0];
        pw[(nt * 6 + 1) * 64] = a.u[1];
        pw[(nt * 6 + 2) * 64] = a.u[2];
        pw[(nt * 6 + 3) * 64] = a.u[3];
        pw[(nt * 6 + 4) * 64] = c.u[0];
        pw[(nt * 6 + 5) * 64] = c.u[1];
    }
}

// ---------------------------------------------------------------------------
// Phase 2 + gold, merged: one block per batch; wave 0 chains the NCK chunk
// matrices with renorm, combines with gold. y[4t+r] <-> row 16t+4g+r.
// ---------------------------------------------------------------------------
__global__ __launch_bounds__(256)
void crf_finish(const float* __restrict__ em, const int* __restrict__ tags,
                const int* __restrict__ mask, const float* __restrict__ trn,
                const float* __restrict__ stt, const float* __restrict__ ent,
                const float* __restrict__ pws, float* __restrict__ out)
{
    __shared__ float red[256];
    __shared__ float alpha[Tt];
    const int b = blockIdx.x, t = threadIdx.x;

    // gold partial
    const int* tg = tags + (size_t)b * Ss;
    float local = 0.0f;
    for (int s = t; s < Ss; s += 256) {
        if (s > 0) {
            int pv = tg[s - 1], cu = tg[s];
            float mf = (float)mask[(size_t)b * Ss + s];
            local += (trn[pv * Tt + cu] + em[((size_t)b * Ss + s) * Tt + cu]) * mf;
        }
    }
    if (t == 0) {
        int t0 = tg[0];
        local += stt[t0] + em[(size_t)b * Ss * Tt + t0];
        local += ent[tg[Ss - 1]];
    }
    red[t] = local;
    __syncthreads();
    if (t < 128) red[t] += red[t + 128];
    __syncthreads();

    if (t < 64) {
        const int l = t, c0 = l & 15, g = l >> 4;
        float gsum = red[l] + red[l + 64];
#pragma unroll
        for (int m = 32; m >= 1; m >>= 1) gsum += __shfl_xor(gsum, m);

        // alpha init (natural): alpha[i] = exp(stt[i] + em[b,0,i] - C)
        if (l < Tt) alpha[l] = __expf(stt[l] + em[(size_t)b * Ss * Tt + l] - C_SHIFT);

        float acc = 0.0f;
        const unsigned* pw = (const unsigned*)pws + (size_t)b * NCK * 1152 + l;
        for (int ck = 0; ck < NCK; ++ck) {
            float y[12];
#pragma unroll
            for (int i = 0; i < 12; ++i) y[i] = 0.0f;
#pragma unroll
            for (int nt = 0; nt < 3; ++nt) {
                float av = alpha[16 * nt + c0];
                unsigned w[6];
#pragma unroll
                for (int q = 0; q < 6; ++q) w[q] = pw[(size_t)ck * 1152 + (nt * 6 + q) * 64];
                // q=0,1 -> y[0..3]; q=2,3 -> y[4..7]; q=4,5 -> y[8..11]
#pragma unroll
                for (int q = 0; q < 6; ++q) {
                    y[2 * q]     += bfu(w[q] << 16)         * av;
                    y[2 * q + 1] += bfu(w[q] & 0xFFFF0000u) * av;
                }
            }
#pragma unroll
            for (int m = 1; m <= 8; m <<= 1)
#pragma unroll
                for (int i = 0; i < 12; ++i) y[i] += __shfl_xor(y[i], m);
            float mx = y[0];
#pragma unroll
            for (int i = 1; i < 12; ++i) mx = fmaxf(mx, y[i]);
            mx = fmaxf(mx, __shfl_xor(mx, 16));
            mx = fmaxf(mx, __shfl_xor(mx, 32));
            acc += __logf(mx);
            float rm = 1.0f / mx;
            if (c0 == 0) {
#pragma unroll
                for (int tt = 0; tt < 3; ++tt)
#pragma unroll
                    for (int rr = 0; rr < 4; ++rr)
                        alpha[16 * tt + 4 * g + rr] = y[4 * tt + rr] * rm;
            }
        }
        // fwd = log(sum alpha * exp(ent)) + acc + S*C
        float part = (l < Tt) ? alpha[l] * __expf(ent[l]) : 0.0f;
#pragma unroll
        for (int m = 32; m >= 1; m >>= 1) part += __shfl_xor(part, m);
        if (t == 0) {
            float fwd = __logf(part) + acc + (float)Ss * C_SHIFT;
            atomicAdd(out, (fwd - gsum) * (1.0f / 256.0f));
        }
    }
}

// ---------------------------------------------------------------------------
extern "C" void kernel_launch(void* const* d_in, const int* in_sizes, int n_in,
                              void* d_out, int out_size, void* d_ws, size_t ws_size,
                              hipStream_t stream)
{
    const float* em  = (const float*)d_in[0];
    const int* tags  = (const int*)d_in[1];
    const int* mask  = (const int*)d_in[2];
    const float* trn = (const float*)d_in[3];
    const float* stt = (const float*)d_in[4];
    const float* ent = (const float*)d_in[5];
    float* out = (float*)d_out;
    float* pws = (float*)d_ws;   // 6144 waves x 4608 B = 28.3 MB

    crf_scan<<<1536, 256, 0, stream>>>(em, trn, pws, out);
    crf_finish<<<256, 256, 0, stream>>>(em, tags, mask, trn, stt, ent, pws, out);
}

// Round 8
// 251.257 us; speedup vs baseline: 1.3799x; 1.0198x over previous
//
#include <hip/hip_runtime.h>
#include <hip/hip_bf16.h>

#define Bb 256
#define Ss 2048
#define Tt 48
#define NCK 24           // chunks per batch (pws = 28.3 MB)
#define CLEN 86          // steps per chunk (last chunk: 69)

static constexpr float C_SHIFT = 4.875f;  // ~ln(48)+1: per-step growth ~= 1

typedef float f4   __attribute__((ext_vector_type(4)));
typedef short s4h  __attribute__((ext_vector_type(4)));
typedef __bf16 bf16x8 __attribute__((ext_vector_type(8)));

union U32x4 { unsigned u[4]; bf16x8 v; };
union U32x2 { unsigned u[2]; s4h v; };

__device__ __forceinline__ unsigned pk_trunc(float lo, float hi) {
    unsigned a = __builtin_bit_cast(unsigned, lo);
    unsigned b = __builtin_bit_cast(unsigned, hi);
#if __has_builtin(__builtin_amdgcn_perm)
    return __builtin_amdgcn_perm(b, a, 0x07060302u);
#else
    return (b & 0xFFFF0000u) | (a >> 16);
#endif
}
__device__ __forceinline__ unsigned pk_rne(float lo, float hi) {
    __hip_bfloat162 h = __float22bfloat162_rn(make_float2(lo, hi));
    union { __hip_bfloat16 b[2]; unsigned u; } t;
    t.b[0] = h.x; t.b[1] = h.y;
    return t.u;
}
__device__ __forceinline__ float bfu(unsigned u) { return __builtin_bit_cast(float, u); }

// k-slot bijection for the x32 operands: slot (g,j) holds k = sig32(g,j).
// Chosen so the step's C-output (row = 16*mt + 4g + r at lane-quad g) repacks
// into next step's B operands with ZERO cross-lane traffic:
//   sig32(g,j) = 16*(j>>2) + 4g + (j&3)   (j<4 -> rows of m-tile 0, j>=4 -> m-tile 1)
//   x16 frag covers rows 32..47: slot (g,r) = 32 + 4g + r  (m-tile 2)
// A and B use the same slot convention, so the MFMA contracts correctly for
// ANY bijection (hardware pairs equal slots of A and B).
__device__ __forceinline__ int sig32(int g, int j) {
    return 16 * (j >> 2) + 4 * g + (j & 3);
}

#define MFMA32(a,b,c) __builtin_amdgcn_mfma_f32_16x16x32_bf16(a, b, c, 0, 0, 0)
#define MFMA16(a,b,c) __builtin_amdgcn_mfma_f32_16x16x16bf16_1k(a, b, c, 0, 0, 0)

// ---------------------------------------------------------------------------
// One scan step: per n-tile, D = A32*B32 (K rows 0..31) + A16*B16 (rows
// 32..47), rowscale by e, repack (natural row space throughout).
// ---------------------------------------------------------------------------
__device__ __forceinline__ void scan_step(const bf16x8 (&A32)[3], const s4h (&A16)[3],
                                          bf16x8 (&B32)[3], s4h (&B16)[3],
                                          const float* __restrict__ eb)
{
    f4 e0 = *(const f4*)(eb);          // e[4g + 0..3]      (rows of m-tile 0)
    f4 e1 = *(const f4*)(eb + 16);     // e[16 + 4g + 0..3] (m-tile 1)
    f4 e2 = *(const f4*)(eb + 32);     // e[32 + 4g + 0..3] (m-tile 2)
    const f4 z = {0.f, 0.f, 0.f, 0.f};
#pragma unroll
    for (int nt = 0; nt < 3; ++nt) {
        f4 c0v = MFMA32(A32[0], B32[nt], z);
        f4 c1v = MFMA32(A32[1], B32[nt], z);
        f4 c2v = MFMA32(A32[2], B32[nt], z);
        c0v = MFMA16(A16[0], B16[nt], c0v);
        c1v = MFMA16(A16[1], B16[nt], c1v);
        c2v = MFMA16(A16[2], B16[nt], c2v);
        // repack: B32 slot j<4 <- m-tile0 reg j (row 4g+j); j>=4 <- m-tile1 reg j-4
        U32x4 nb;
        nb.u[0] = pk_trunc(c0v[0] * e0[0], c0v[1] * e0[1]);
        nb.u[1] = pk_trunc(c0v[2] * e0[2], c0v[3] * e0[3]);
        nb.u[2] = pk_trunc(c1v[0] * e1[0], c1v[1] * e1[1]);
        nb.u[3] = pk_trunc(c1v[2] * e1[2], c1v[3] * e1[3]);
        B32[nt] = nb.v;
        U32x2 nc;
        nc.u[0] = pk_trunc(c2v[0] * e2[0], c2v[1] * e2[1]);
        nc.u[1] = pk_trunc(c2v[2] * e2[2], c2v[3] * e2[3]);
        B16[nt] = nc.v;
    }
}

// ---------------------------------------------------------------------------
// Phase 1: one wave per (batch, chunk): 48x48 transfer-matrix product in regs.
// 1536 blocks x 4 waves = 6144 waves = 256 batches x 24 chunks.
// launch_bounds(256,3): r5 proved this gives VGPR=64, zero spill. Residency
// is then VGPR-limited at ~16 waves/CU (4 blocks/CU) — occupancy comes from
// the 6-blocks/CU grid, NOT from a tighter bound (r7: (256,6) made the
// allocator shrink to 40 VGPR + ~24 MB scratch spill; r6: (256,8) -> 32 VGPR
// + 300 MB spill).
// ---------------------------------------------------------------------------
__global__ __launch_bounds__(256, 3)
void crf_scan(const float* __restrict__ em, const float* __restrict__ trn,
              float* __restrict__ pws, float* __restrict__ outz)
{
    __shared__ float lex[4][16 * Tt];          // per-wave 16-step exp(em) buffer
    const int tid = threadIdx.x, wv = tid >> 6, l = tid & 63;
    const int c0 = l & 15, g = l >> 4;
    const int wid = blockIdx.x * 4 + wv;
    const int b = wid / NCK, ck = wid % NCK;
    if (blockIdx.x == 0 && tid == 0) outz[0] = 0.0f;   // zero d_out for finish

    // A-frags: A32[mt] slot (g,j) = exp(trn[sig32(g,j)][16mt+c0])
    //          A16[mt] slot (g,j) = exp(trn[32+4g+j][16mt+c0])
    bf16x8 A32[3]; s4h A16[3];
#pragma unroll
    for (int mt = 0; mt < 3; ++mt) {
        float v[8];
#pragma unroll
        for (int j = 0; j < 8; ++j)
            v[j] = __expf(trn[sig32(g, j) * Tt + 16 * mt + c0]);
        U32x4 a;
        a.u[0] = pk_rne(v[0], v[1]); a.u[1] = pk_rne(v[2], v[3]);
        a.u[2] = pk_rne(v[4], v[5]); a.u[3] = pk_rne(v[6], v[7]);
        A32[mt] = a.v;
        float w0 = __expf(trn[(32 + 4 * g + 0) * Tt + 16 * mt + c0]);
        float w1 = __expf(trn[(32 + 4 * g + 1) * Tt + 16 * mt + c0]);
        float w2 = __expf(trn[(32 + 4 * g + 2) * Tt + 16 * mt + c0]);
        float w3 = __expf(trn[(32 + 4 * g + 3) * Tt + 16 * mt + c0]);
        U32x2 c;
        c.u[0] = pk_rne(w0, w1); c.u[1] = pk_rne(w2, w3);
        A16[mt] = c.v;
    }

    // State init = identity: B32 slot (g,j) hot iff sig32(g,j) == 16nt + c0
    bf16x8 B32[3]; s4h B16[3];
#pragma unroll
    for (int nt = 0; nt < 3; ++nt) {
        U32x4 bi;
#pragma unroll
        for (int q = 0; q < 4; ++q) {
            unsigned lo = (sig32(g, 2 * q)     == 16 * nt + c0) ? 0x3F80u : 0u;
            unsigned hi = (sig32(g, 2 * q + 1) == 16 * nt + c0) ? 0x3F80u : 0u;
            bi.u[q] = lo | (hi << 16);
        }
        B32[nt] = bi.v;
        U32x2 ci;
#pragma unroll
        for (int q = 0; q < 2; ++q) {
            unsigned lo = (nt == 2 && 4 * g + 2 * q     == c0) ? 0x3F80u : 0u;
            unsigned hi = (nt == 2 && 4 * g + 2 * q + 1 == c0) ? 0x3F80u : 0u;
            ci.u[q] = lo | (hi << 16);
        }
        B16[nt] = ci.v;
    }

    const int total = (ck == NCK - 1) ? (Ss - 1 - ck * CLEN) : CLEN;  // 86 / 69
    const int s0 = ck * CLEN + 1;
    const float* emb = em + (size_t)b * (Ss * Tt);
    float* lw = &lex[wv][0];
    const float* lexg = lw + g * 4;
    const long lim = (long)Ss * Tt - 4;

    // prefetch sub 0 (early-issued global loads, consumed at loop top)
    f4 r[3];
#pragma unroll
    for (int i = 0; i < 3; ++i) {
        long o = (long)s0 * Tt + l * 4 + i * 256;
        if (o > lim) o = lim;
        r[i] = *(const f4*)(emb + o);
    }

    const int nsub = (total + 15) >> 4;
    for (int sub = 0; sub < nsub; ++sub) {
#pragma unroll
        for (int i = 0; i < 3; ++i)
#pragma unroll
            for (int j = 0; j < 4; ++j) r[i][j] = __expf(r[i][j] - C_SHIFT);
#pragma unroll
        for (int i = 0; i < 3; ++i) *(f4*)(lw + l * 4 + i * 256) = r[i];

        if (sub + 1 < nsub) {        // issue next sub's loads before compute
#pragma unroll
            for (int i = 0; i < 3; ++i) {
                long o = (long)(s0 + (sub + 1) * 16) * Tt + l * 4 + i * 256;
                if (o > lim) o = lim;
                r[i] = *(const f4*)(emb + o);
            }
        }

        int nsteps = total - sub * 16;
        if (nsteps >= 16) {
#pragma unroll
            for (int u = 0; u < 16; ++u)
                scan_step(A32, A16, B32, B16, lexg + u * Tt);
        } else {
            for (int u = 0; u < nsteps; ++u)
                scan_step(A32, A16, B32, B16, lexg + u * Tt);
        }
    }

    // store 18 u32/lane, coalesced. Word (nt*6+q): q=0..3 -> rows sig32(g,2q),
    // sig32(g,2q+1); q=4,5 -> rows 32+4g+{0,1},{2,3}; col = 16nt+c0.
    unsigned* pw = (unsigned*)pws + (size_t)wid * 1152 + l;
#pragma unroll
    for (int nt = 0; nt < 3; ++nt) {
        U32x4 a; a.v = B32[nt];
        U32x2 c; c.v = B16[nt];
        pw[(nt * 6 + 0) * 64] = a.u[0];
        pw[(nt * 6 + 1) * 64] = a.u[1];
        pw[(nt * 6 + 2) * 64] = a.u[2];
        pw[(nt * 6 + 3) * 64] = a.u[3];
        pw[(nt * 6 + 4) * 64] = c.u[0];
        pw[(nt * 6 + 5) * 64] = c.u[1];
    }
}

// ---------------------------------------------------------------------------
// Phase 2 + gold, merged: one block per batch; wave 0 chains the NCK chunk
// matrices with renorm, combines with gold. y[4t+r] <-> row 16t+4g+r.
// ---------------------------------------------------------------------------
__global__ __launch_bounds__(256)
void crf_finish(const float* __restrict__ em, const int* __restrict__ tags,
                const int* __restrict__ mask, const float* __restrict__ trn,
                const float* __restrict__ stt, const float* __restrict__ ent,
                const float* __restrict__ pws, float* __restrict__ out)
{
    __shared__ float red[256];
    __shared__ float alpha[Tt];
    const int b = blockIdx.x, t = threadIdx.x;

    // gold partial
    const int* tg = tags + (size_t)b * Ss;
    float local = 0.0f;
    for (int s = t; s < Ss; s += 256) {
        if (s > 0) {
            int pv = tg[s - 1], cu = tg[s];
            float mf = (float)mask[(size_t)b * Ss + s];
            local += (trn[pv * Tt + cu] + em[((size_t)b * Ss + s) * Tt + cu]) * mf;
        }
    }
    if (t == 0) {
        int t0 = tg[0];
        local += stt[t0] + em[(size_t)b * Ss * Tt + t0];
        local += ent[tg[Ss - 1]];
    }
    red[t] = local;
    __syncthreads();
    if (t < 128) red[t] += red[t + 128];
    __syncthreads();

    if (t < 64) {
        const int l = t, c0 = l & 15, g = l >> 4;
        float gsum = red[l] + red[l + 64];
#pragma unroll
        for (int m = 32; m >= 1; m >>= 1) gsum += __shfl_xor(gsum, m);

        // alpha init (natural): alpha[i] = exp(stt[i] + em[b,0,i] - C)
        if (l < Tt) alpha[l] = __expf(stt[l] + em[(size_t)b * Ss * Tt + l] - C_SHIFT);

        float acc = 0.0f;
        const unsigned* pw = (const unsigned*)pws + (size_t)b * NCK * 1152 + l;
        for (int ck = 0; ck < NCK; ++ck) {
            float y[12];
#pragma unroll
            for (int i = 0; i < 12; ++i) y[i] = 0.0f;
#pragma unroll
            for (int nt = 0; nt < 3; ++nt) {
                float av = alpha[16 * nt + c0];
                unsigned w[6];
#pragma unroll
                for (int q = 0; q < 6; ++q) w[q] = pw[(size_t)ck * 1152 + (nt * 6 + q) * 64];
                // q=0,1 -> y[0..3]; q=2,3 -> y[4..7]; q=4,5 -> y[8..11]
#pragma unroll
                for (int q = 0; q < 6; ++q) {
                    y[2 * q]     += bfu(w[q] << 16)         * av;
                    y[2 * q + 1] += bfu(w[q] & 0xFFFF0000u) * av;
                }
            }
#pragma unroll
            for (int m = 1; m <= 8; m <<= 1)
#pragma unroll
                for (int i = 0; i < 12; ++i) y[i] += __shfl_xor(y[i], m);
            float mx = y[0];
#pragma unroll
            for (int i = 1; i < 12; ++i) mx = fmaxf(mx, y[i]);
            mx = fmaxf(mx, __shfl_xor(mx, 16));
            mx = fmaxf(mx, __shfl_xor(mx, 32));
            acc += __logf(mx);
            float rm = 1.0f / mx;
            if (c0 == 0) {
#pragma unroll
                for (int tt = 0; tt < 3; ++tt)
#pragma unroll
                    for (int rr = 0; rr < 4; ++rr)
                        alpha[16 * tt + 4 * g + rr] = y[4 * tt + rr] * rm;
            }
        }
        // fwd = log(sum alpha * exp(ent)) + acc + S*C
        float part = (l < Tt) ? alpha[l] * __expf(ent[l]) : 0.0f;
#pragma unroll
        for (int m = 32; m >= 1; m >>= 1) part += __shfl_xor(part, m);
        if (t == 0) {
            float fwd = __logf(part) + acc + (float)Ss * C_SHIFT;
            atomicAdd(out, (fwd - gsum) * (1.0f / 256.0f));
        }
    }
}

// ---------------------------------------------------------------------------
extern "C" void kernel_launch(void* const* d_in, const int* in_sizes, int n_in,
                              void* d_out, int out_size, void* d_ws, size_t ws_size,
                              hipStream_t stream)
{
    const float* em  = (const float*)d_in[0];
    const int* tags  = (const int*)d_in[1];
    const int* mask  = (const int*)d_in[2];
    const float* trn = (const float*)d_in[3];
    const float* stt = (const float*)d_in[4];
    const float* ent = (const float*)d_in[5];
    float* out = (float*)d_out;
    float* pws = (float*)d_ws;   // 6144 waves x 4608 B = 28.3 MB

    crf_scan<<<1536, 256, 0, stream>>>(em, trn, pws, out);
    crf_finish<<<256, 256, 0, stream>>>(em, tags, mask, trn, stt, ent, pws, out);
}